// Round 11
// baseline (313.120 us; speedup 1.0000x reference)
//
#include <hip/hip_runtime.h>
#include <hip/hip_bf16.h>

typedef float f32x4 __attribute__((ext_vector_type(4)));
typedef short s16x8 __attribute__((ext_vector_type(8)));

#define NB   256
#define NU   512
#define ND0  512
#define ND1  1024
#define WROW (ND0 * ND1)   // elements per u-row of w

// ws layout: f32x4 ws4[bid][mf*2+nf][t]  (512 x 16 x 512 f32x4 = 64 MB)
#define WS_BYTES ((size_t)512 * 16 * 512 * 16)

__device__ __forceinline__ unsigned int f2bf_pk(float a, float b) {
  __hip_bfloat16 ha = __float2bfloat16(a);
  __hip_bfloat16 hb = __float2bfloat16(b);
  unsigned short ua, ub;
  __builtin_memcpy(&ua, &ha, 2);
  __builtin_memcpy(&ub, &hb, 2);
  return (unsigned int)ua | ((unsigned int)ub << 16);
}

// CK-style barrier: enforces LDS ordering but does NOT drain vmcnt,
// so register-prefetch global loads stay in flight across it.
__device__ __forceinline__ void block_sync_lds() {
  asm volatile("s_waitcnt lgkmcnt(0)" ::: "memory");
  __builtin_amdgcn_s_barrier();
}

// Seed out[b,u] = bias[u]; atomic-fallback path only.
__global__ __launch_bounds__(256) void init_out(const float* __restrict__ bias,
                                                float* __restrict__ out) {
  int idx = blockIdx.x * 256 + threadIdx.x;
  out[idx] = bias[idx & (NU - 1)];
}

// Reduce kernel (ws path): out[b,u] = bias[u] + sum_ic ws-partial.
__global__ __launch_bounds__(256) void reduce_ws(
    const float* __restrict__ bias, const f32x4* __restrict__ ws4,
    float* __restrict__ out) {
  const int g  = blockIdx.x * 256 + threadIdx.x;   // 128 blocks -> 32768
  const int u  = g & 511;
  const int bh = g >> 9;                           // b>>2, 0..63
  const int wm = bh >> 5, mf = (bh >> 2) & 7, lk = bh & 3;
  const int ntile = u >> 7, wn = (u >> 5) & 3, nf = (u >> 4) & 1, l15 = u & 15;
  const int t  = (wm * 4 + wn) * 64 + lk * 16 + l15;
  const size_t base = (size_t)(mf * 2 + nf) * 512 + t;

  f32x4 s0 = {0, 0, 0, 0}, s1 = {0, 0, 0, 0};
#pragma unroll 8
  for (int ic = 0; ic < 128; ic += 2) {
    s0 += ws4[base + (size_t)((ic + 0) * 4 + ntile) * (16 * 512)];
    s1 += ws4[base + (size_t)((ic + 1) * 4 + ntile) * (16 * 512)];
  }
  f32x4 s = s0 + s1;
  const float bv = bias[u];
  const int b0 = bh * 4;
#pragma unroll
  for (int r = 0; r < 4; ++r)
    out[(size_t)(b0 + r) * NU + u] = s[r] + bv;
}

// out(256x512) = Z(256x524288) @ W^T, Z[b, i*1024+j] = x[b,i]*y[b,j].
// Grid: 512 blocks = 4 u-tiles x 128 K-chunks. Block: 512 thr, 8 waves (2m x 4n).
//
// R11 = R8 (291.8us best) with ONE synth-internal change: rolling y
// double-buffer. R10's null proved the wvn copy-stall is already
// latency-covered; the remaining dead-HBM window is the synth's SERIAL
// y chain (g1's 4 loads wait for g0's consume -- same v[4] registers,
// and R1 proved no 16 spare VGPRs exist to rename). Rolling vA[2]/vB[2]
// (16 VGPR total = v[4], liveness-exact) pipelines the chain: every
// consume's wait is a counted vmcnt(2) leaving the next group in flight;
// only the first consume pays L2 latency. sched_barrier(0) fences pin
// the interleave (no hoist-all-loads pressure spike, no re-serialization).
// Everything outside the synth block is R8 byte-identical.
__global__ __launch_bounds__(512, 4) void bilinear_kern(
    const float* __restrict__ x, const float* __restrict__ y,
    const float* __restrict__ w, float* __restrict__ out,
    float* __restrict__ ws, int use_ws) {
  __shared__ char Alds[32768];   // 256 rows x 128B (64 bf16), XOR-swizzled
  __shared__ char Wlds[16384];   // 128 rows x 128B (64 bf16), XOR-swizzled

  const int t    = threadIdx.x;
  const int lane = t & 63;
  const int l15  = lane & 15;
  const int lk   = lane >> 4;          // 0..3
  const int wid  = t >> 6;             // 0..7
  const int wm   = wid >> 2;           // 0..1  (m-group: rows wm*128)
  const int wn   = wid & 3;            // 0..3  (n-group: cols wn*32)

  const int nt    = blockIdx.x & 3;    // u-tile
  const int ic    = blockIdx.x >> 2;   // K-chunk: i0 in [ic*4, ic*4+4)
  const int off   = (nt << 4) | (ic & 15);   // start phase, 0..63 (R7 stagger)
  const int ucol0 = nt * 128 + wn * 32;

  f32x4 acc[8][2];
#pragma unroll
  for (int mf = 0; mf < 8; ++mf)
#pragma unroll
    for (int nf = 0; nf < 2; ++nf)
#pragma unroll
      for (int r = 0; r < 4; ++r) acc[mf][nf][r] = 0.0f;

  // --- A staging map: thread covers rows ar+32p (p=0..7), floats l15*4..+4 ---
  const int ar   = t >> 4;                        // 0..31
  const int aswz = (ar & 7) << 4;                 // (row&7) invariant under +32p
  const int awr  = ar * 128 + ((l15 * 8) ^ aswz); // +p*4096
  const float* yb = y + (size_t)ar * ND1 + l15 * 4;

  // --- W staging map: thread covers rows wrb+4q (q=0..3), floats l15*4..+4 ---
  const int wrb = wid * 16 + lk;                  // 0..127 (wid*16+lk<128)
  const float* wq = w + (size_t)(nt * 128 + wrb) * WROW + l15 * 4;

  // frag-read swizzle: frag rows are l15 mod 8 in both tiles
  const int afswz = (l15 & 7) << 4;

  // ---- prologue: prefetch step-0's W and its x column (staggered phase) ----
  f32x4 wv[4], wvn[4];
  const int ii0 = ic * 4 + (off >> 4);
  {
    const float* p0 = wq + (size_t)ii0 * ND1 + (off & 15) * 64;
#pragma unroll
    for (int q = 0; q < 4; ++q)
      wv[q] = __builtin_nontemporal_load((const f32x4*)(p0 + (size_t)q * 4 * WROW));
  }
  float xv[8];
#pragma unroll
  for (int p = 0; p < 8; ++p)
    xv[p] = x[(size_t)(ar + 32 * p) * ND0 + ii0];

// consume one 2-row group: rows P0,P0+1 (compile-time after unroll)
#define SYNTH_PAIR(V, P0)                                                     \
  {                                                                           \
    _Pragma("unroll")                                                         \
    for (int q2 = 0; q2 < 2; ++q2) {                                          \
      const int p = (P0) + q2;                                                \
      unsigned long long pk =                                                 \
          (unsigned long long)f2bf_pk(xv[p] * V[q2][0], xv[p] * V[q2][1]) |   \
          ((unsigned long long)f2bf_pk(xv[p] * V[q2][2], xv[p] * V[q2][3])    \
           << 32);                                                            \
      *(unsigned long long*)(Alds + awr + p * 4096) = pk;                     \
    }                                                                         \
  }

  for (int it = 0; it < 64; ++it) {
    const int s  = (it + off) & 63;    // staggered sweep position
    const int j0 = (s & 15) * 64;

    block_sync_lds();   // barrier1: previous tiles fully consumed

    // ---- A-tile synth, rolling y double-buffer (R11) ----
    // issue A,B -> consume A -> issue A' -> consume B -> issue B'
    // -> consume A' -> consume B'. Each consume waits vmcnt(2).
    {
      f32x4 vA[2], vB[2];
      vA[0] = *(const f32x4*)(yb + (size_t)0 * 32 * ND1 + j0);
      vA[1] = *(const f32x4*)(yb + (size_t)1 * 32 * ND1 + j0);
      vB[0] = *(const f32x4*)(yb + (size_t)2 * 32 * ND1 + j0);
      vB[1] = *(const f32x4*)(yb + (size_t)3 * 32 * ND1 + j0);
      __builtin_amdgcn_sched_barrier(0);
      SYNTH_PAIR(vA, 0)
      __builtin_amdgcn_sched_barrier(0);
      vA[0] = *(const f32x4*)(yb + (size_t)4 * 32 * ND1 + j0);
      vA[1] = *(const f32x4*)(yb + (size_t)5 * 32 * ND1 + j0);
      __builtin_amdgcn_sched_barrier(0);
      SYNTH_PAIR(vB, 2)
      __builtin_amdgcn_sched_barrier(0);
      vB[0] = *(const f32x4*)(yb + (size_t)6 * 32 * ND1 + j0);
      vB[1] = *(const f32x4*)(yb + (size_t)7 * 32 * ND1 + j0);
      __builtin_amdgcn_sched_barrier(0);
      SYNTH_PAIR(vA, 4)
      __builtin_amdgcn_sched_barrier(0);
      SYNTH_PAIR(vB, 6)
    }

    // ---- W-tile pack: fp32 regs -> bf16 LDS (swizzled); waits on wv here ----
#pragma unroll
    for (int q = 0; q < 4; ++q) {
      const int row  = wrb + 4 * q;
      const int byte = row * 128 + ((l15 * 8) ^ ((row & 7) << 4));
      unsigned long long pk =
          (unsigned long long)f2bf_pk(wv[q][0], wv[q][1]) |
          ((unsigned long long)f2bf_pk(wv[q][2], wv[q][3]) << 32);
      *(unsigned long long*)(Wlds + byte) = pk;
    }

    // ---- prefetch next step (stays in flight across barrier2 + MFMA) ----
    if (it < 63) {
      const int sn = (s + 1) & 63;
      const int ii = ic * 4 + (sn >> 4);
      const int jn = (sn & 15) * 64;
      const float* pn = wq + (size_t)ii * ND1 + jn;
#pragma unroll
      for (int q = 0; q < 4; ++q)
        wvn[q] = __builtin_nontemporal_load((const f32x4*)(pn + (size_t)q * 4 * WROW));
      if ((s & 15) == 15) {
#pragma unroll
        for (int pp = 0; pp < 8; ++pp)
          xv[pp] = x[(size_t)(ar + 32 * pp) * ND0 + ii];
      }
    }

    block_sync_lds();   // barrier2: tiles visible

    // ---- MFMA over BK=64 (two k-steps of 32) ----
#pragma unroll
    for (int ks = 0; ks < 2; ++ks) {
      const int kcol = ks * 64;
      s16x8 bf[2];
#pragma unroll
      for (int nf = 0; nf < 2; ++nf) {
        const int row = wn * 32 + nf * 16 + l15;
        bf[nf] = *(const s16x8*)(Wlds + row * 128 + ((kcol + lk * 16) ^ afswz));
      }
#pragma unroll
      for (int mf = 0; mf < 8; ++mf) {
        const int row = wm * 128 + mf * 16 + l15;
        s16x8 af = *(const s16x8*)(Alds + row * 128 + ((kcol + lk * 16) ^ afswz));
        acc[mf][0] = __builtin_amdgcn_mfma_f32_16x16x32_bf16(af, bf[0], acc[mf][0], 0, 0, 0);
        acc[mf][1] = __builtin_amdgcn_mfma_f32_16x16x32_bf16(af, bf[1], acc[mf][1], 0, 0, 0);
      }
    }

#pragma unroll
    for (int q = 0; q < 4; ++q) wv[q] = wvn[q];
  }
#undef SYNTH_PAIR

  // ---- epilogue (R8) ----
  if (use_ws) {
    f32x4* ws4 = (f32x4*)ws + (size_t)blockIdx.x * (16 * 512) + t;
#pragma unroll
    for (int mf = 0; mf < 8; ++mf)
#pragma unroll
      for (int nf = 0; nf < 2; ++nf)
        __builtin_nontemporal_store(acc[mf][nf], ws4 + (mf * 2 + nf) * 512);
  } else {
#pragma unroll
    for (int mf = 0; mf < 8; ++mf) {
      const int grow = wm * 128 + mf * 16 + lk * 4;
#pragma unroll
      for (int nf = 0; nf < 2; ++nf) {
        const int gcol = ucol0 + nf * 16 + l15;
#pragma unroll
        for (int r = 0; r < 4; ++r) {
          atomicAdd(out + (size_t)(grow + r) * NU + gcol, acc[mf][nf][r]);
        }
      }
    }
  }
}

extern "C" void kernel_launch(void* const* d_in, const int* in_sizes, int n_in,
                              void* d_out, int out_size, void* d_ws, size_t ws_size,
                              hipStream_t stream) {
  const float* x    = (const float*)d_in[0];
  const float* y    = (const float*)d_in[1];
  const float* w    = (const float*)d_in[2];
  const float* bias = (const float*)d_in[3];
  float* out = (float*)d_out;

  const bool use_ws = (d_ws != nullptr) && (ws_size >= WS_BYTES);
  if (use_ws) {
    bilinear_kern<<<512, 512, 0, stream>>>(x, y, w, out, (float*)d_ws, 1);
    reduce_ws<<<128, 256, 0, stream>>>(bias, (const f32x4*)d_ws, out);
  } else {
    init_out<<<512, 256, 0, stream>>>(bias, out);
    bilinear_kern<<<512, 512, 0, stream>>>(x, y, w, out, nullptr, 0);
  }
}

// Round 12
// 292.886 us; speedup vs baseline: 1.0691x; 1.0691x over previous
//
#include <hip/hip_runtime.h>
#include <hip/hip_bf16.h>

typedef float f32x4 __attribute__((ext_vector_type(4)));
typedef short s16x8 __attribute__((ext_vector_type(8)));

#define NB   256
#define NU   512
#define ND0  512
#define ND1  1024
#define WROW (ND0 * ND1)   // elements per u-row of w

// ws layout: f32x4 ws4[bid][mf*2+nf][t]  (512 x 16 x 512 f32x4 = 64 MB)
#define WS_BYTES ((size_t)512 * 16 * 512 * 16)

__device__ __forceinline__ unsigned int f2bf_pk(float a, float b) {
  __hip_bfloat16 ha = __float2bfloat16(a);
  __hip_bfloat16 hb = __float2bfloat16(b);
  unsigned short ua, ub;
  __builtin_memcpy(&ua, &ha, 2);
  __builtin_memcpy(&ub, &hb, 2);
  return (unsigned int)ua | ((unsigned int)ub << 16);
}

// CK-style barrier: enforces LDS ordering but does NOT drain vmcnt,
// so register-prefetch global loads stay in flight across it.
__device__ __forceinline__ void block_sync_lds() {
  asm volatile("s_waitcnt lgkmcnt(0)" ::: "memory");
  __builtin_amdgcn_s_barrier();
}

// Seed out[b,u] = bias[u]; atomic-fallback path only.
__global__ __launch_bounds__(256) void init_out(const float* __restrict__ bias,
                                                float* __restrict__ out) {
  int idx = blockIdx.x * 256 + threadIdx.x;
  out[idx] = bias[idx & (NU - 1)];
}

// Reduce kernel (ws path): out[b,u] = bias[u] + sum_ic ws-partial.
__global__ __launch_bounds__(256) void reduce_ws(
    const float* __restrict__ bias, const f32x4* __restrict__ ws4,
    float* __restrict__ out) {
  const int g  = blockIdx.x * 256 + threadIdx.x;   // 128 blocks -> 32768
  const int u  = g & 511;
  const int bh = g >> 9;                           // b>>2, 0..63
  const int wm = bh >> 5, mf = (bh >> 2) & 7, lk = bh & 3;
  const int ntile = u >> 7, wn = (u >> 5) & 3, nf = (u >> 4) & 1, l15 = u & 15;
  const int t  = (wm * 4 + wn) * 64 + lk * 16 + l15;
  const size_t base = (size_t)(mf * 2 + nf) * 512 + t;

  f32x4 s0 = {0, 0, 0, 0}, s1 = {0, 0, 0, 0};
#pragma unroll 8
  for (int ic = 0; ic < 128; ic += 2) {
    s0 += ws4[base + (size_t)((ic + 0) * 4 + ntile) * (16 * 512)];
    s1 += ws4[base + (size_t)((ic + 1) * 4 + ntile) * (16 * 512)];
  }
  f32x4 s = s0 + s1;
  const float bv = bias[u];
  const int b0 = bh * 4;
#pragma unroll
  for (int r = 0; r < 4; ++r)
    out[(size_t)(b0 + r) * NU + u] = s[r] + bv;
}

// out(256x512) = Z(256x524288) @ W^T, Z[b, i*1024+j] = x[b,i]*y[b,j].
// Grid: 512 blocks = 4 u-tiles (BN=128) x 128 K-chunks (4 i0's x full j each).
// Block: 512 threads, 8 waves (2m x 4n); per-wave 8 m-frags x 2 n-frags.
//
// FINAL (R8 artifact, 291.8us; best of 12 rounds). Composition of the
// verified wins on the original 310.6us baseline:
//  - R3: W loads NONTEMPORAL (single-use stream must not evict L2-resident
//    y working set): -13us.
//  - R7: per-block start-phase stagger off=(nt<<4)|(ic&15) decorrelating
//    same-ic DRAM bursts: -2.5us.
//  - R8: ws-partials epilogue (coalesced nt stores + reduce kernel)
//    replacing 16.7M atomics + serialized init_out: -3.3us.
// The loop body/schedule is the R3 local optimum. Structural attacks all
// regressed and are documented dead ends: register pipeline depth-2
// (VGPR cliff at launch_bounds(512,4): R1/R2), global_load_lds staging
// (occupancy/fp32-frag tax at 1024t: R4/R5; barrier-per-BK32 tax at
// 512t: R9), fenced issue-order moves (vmem single-FIFO retirement:
// R6/R10), synth-internal y pipelining (scheduler-freedom loss: R11).
// Remaining gap to the 170us W-read floor (1.72x) is bound by the
// single-vmcnt-FIFO + VGPR-cliff structure; next step would be a
// different decomposition (y-in-LDS reuse or wave specialization),
// not an edit of this loop.
__global__ __launch_bounds__(512, 4) void bilinear_kern(
    const float* __restrict__ x, const float* __restrict__ y,
    const float* __restrict__ w, float* __restrict__ out,
    float* __restrict__ ws, int use_ws) {
  __shared__ char Alds[32768];   // 256 rows x 128B (64 bf16), XOR-swizzled
  __shared__ char Wlds[16384];   // 128 rows x 128B (64 bf16), XOR-swizzled

  const int t    = threadIdx.x;
  const int lane = t & 63;
  const int l15  = lane & 15;
  const int lk   = lane >> 4;          // 0..3
  const int wid  = t >> 6;             // 0..7
  const int wm   = wid >> 2;           // 0..1  (m-group: rows wm*128)
  const int wn   = wid & 3;            // 0..3  (n-group: cols wn*32)

  const int nt    = blockIdx.x & 3;    // u-tile
  const int ic    = blockIdx.x >> 2;   // K-chunk: i0 in [ic*4, ic*4+4)
  const int off   = (nt << 4) | (ic & 15);   // start phase, 0..63 (R7 stagger)
  const int ucol0 = nt * 128 + wn * 32;

  f32x4 acc[8][2];
#pragma unroll
  for (int mf = 0; mf < 8; ++mf)
#pragma unroll
    for (int nf = 0; nf < 2; ++nf)
#pragma unroll
      for (int r = 0; r < 4; ++r) acc[mf][nf][r] = 0.0f;

  // --- A staging map: thread covers rows ar+32p (p=0..7), floats l15*4..+4 ---
  const int ar   = t >> 4;                        // 0..31
  const int aswz = (ar & 7) << 4;                 // (row&7) invariant under +32p
  const int awr  = ar * 128 + ((l15 * 8) ^ aswz); // +p*4096
  const float* yb = y + (size_t)ar * ND1 + l15 * 4;

  // --- W staging map: thread covers rows wrb+4q (q=0..3), floats l15*4..+4 ---
  const int wrb = wid * 16 + lk;                  // 0..127 (wid*16+lk<128)
  const float* wq = w + (size_t)(nt * 128 + wrb) * WROW + l15 * 4;

  // frag-read swizzle: frag rows are l15 mod 8 in both tiles
  const int afswz = (l15 & 7) << 4;

  // ---- prologue: prefetch step-0's W and its x column (staggered phase) ----
  f32x4 wv[4], wvn[4];
  const int ii0 = ic * 4 + (off >> 4);
  {
    const float* p0 = wq + (size_t)ii0 * ND1 + (off & 15) * 64;
#pragma unroll
    for (int q = 0; q < 4; ++q)
      wv[q] = __builtin_nontemporal_load((const f32x4*)(p0 + (size_t)q * 4 * WROW));
  }
  float xv[8];
#pragma unroll
  for (int p = 0; p < 8; ++p)
    xv[p] = x[(size_t)(ar + 32 * p) * ND0 + ii0];

  for (int it = 0; it < 64; ++it) {
    const int s  = (it + off) & 63;    // staggered sweep position
    const int j0 = (s & 15) * 64;

    block_sync_lds();   // barrier1: previous tiles fully consumed

    // ---- A-tile synth: SY[b,jj] = bf16(x[b,i0]*y[b,j0+jj]) ----
#pragma unroll
    for (int g = 0; g < 2; ++g) {
      f32x4 v[4];
#pragma unroll
      for (int pp = 0; pp < 4; ++pp)
        v[pp] = *(const f32x4*)(yb + (size_t)(g * 4 + pp) * 32 * ND1 + j0);
#pragma unroll
      for (int pp = 0; pp < 4; ++pp) {
        const int p = g * 4 + pp;
        unsigned long long pk =
            (unsigned long long)f2bf_pk(xv[p] * v[pp][0], xv[p] * v[pp][1]) |
            ((unsigned long long)f2bf_pk(xv[p] * v[pp][2], xv[p] * v[pp][3]) << 32);
        *(unsigned long long*)(Alds + awr + p * 4096) = pk;
      }
    }

    // ---- W-tile pack: fp32 regs -> bf16 LDS (swizzled); waits on wv here ----
#pragma unroll
    for (int q = 0; q < 4; ++q) {
      const int row  = wrb + 4 * q;
      const int byte = row * 128 + ((l15 * 8) ^ ((row & 7) << 4));
      unsigned long long pk =
          (unsigned long long)f2bf_pk(wv[q][0], wv[q][1]) |
          ((unsigned long long)f2bf_pk(wv[q][2], wv[q][3]) << 32);
      *(unsigned long long*)(Wlds + byte) = pk;
    }

    // ---- prefetch next step (stays in flight across barrier2 + MFMA) ----
    if (it < 63) {
      const int sn = (s + 1) & 63;
      const int ii = ic * 4 + (sn >> 4);
      const int jn = (sn & 15) * 64;
      const float* pn = wq + (size_t)ii * ND1 + jn;
#pragma unroll
      for (int q = 0; q < 4; ++q)
        wvn[q] = __builtin_nontemporal_load((const f32x4*)(pn + (size_t)q * 4 * WROW));
      if ((s & 15) == 15) {
#pragma unroll
        for (int pp = 0; pp < 8; ++pp)
          xv[pp] = x[(size_t)(ar + 32 * pp) * ND0 + ii];
      }
    }

    block_sync_lds();   // barrier2: tiles visible

    // ---- MFMA over BK=64 (two k-steps of 32) ----
#pragma unroll
    for (int ks = 0; ks < 2; ++ks) {
      const int kcol = ks * 64;
      s16x8 bf[2];
#pragma unroll
      for (int nf = 0; nf < 2; ++nf) {
        const int row = wn * 32 + nf * 16 + l15;
        bf[nf] = *(const s16x8*)(Wlds + row * 128 + ((kcol + lk * 16) ^ afswz));
      }
#pragma unroll
      for (int mf = 0; mf < 8; ++mf) {
        const int row = wm * 128 + mf * 16 + l15;
        s16x8 af = *(const s16x8*)(Alds + row * 128 + ((kcol + lk * 16) ^ afswz));
        acc[mf][0] = __builtin_amdgcn_mfma_f32_16x16x32_bf16(af, bf[0], acc[mf][0], 0, 0, 0);
        acc[mf][1] = __builtin_amdgcn_mfma_f32_16x16x32_bf16(af, bf[1], acc[mf][1], 0, 0, 0);
      }
    }

#pragma unroll
    for (int q = 0; q < 4; ++q) wv[q] = wvn[q];
  }

  // ---- epilogue (R8) ----
  if (use_ws) {
    f32x4* ws4 = (f32x4*)ws + (size_t)blockIdx.x * (16 * 512) + t;
#pragma unroll
    for (int mf = 0; mf < 8; ++mf)
#pragma unroll
      for (int nf = 0; nf < 2; ++nf)
        __builtin_nontemporal_store(acc[mf][nf], ws4 + (mf * 2 + nf) * 512);
  } else {
#pragma unroll
    for (int mf = 0; mf < 8; ++mf) {
      const int grow = wm * 128 + mf * 16 + lk * 4;
#pragma unroll
      for (int nf = 0; nf < 2; ++nf) {
        const int gcol = ucol0 + nf * 16 + l15;
#pragma unroll
        for (int r = 0; r < 4; ++r) {
          atomicAdd(out + (size_t)(grow + r) * NU + gcol, acc[mf][nf][r]);
        }
      }
    }
  }
}

extern "C" void kernel_launch(void* const* d_in, const int* in_sizes, int n_in,
                              void* d_out, int out_size, void* d_ws, size_t ws_size,
                              hipStream_t stream) {
  const float* x    = (const float*)d_in[0];
  const float* y    = (const float*)d_in[1];
  const float* w    = (const float*)d_in[2];
  const float* bias = (const float*)d_in[3];
  float* out = (float*)d_out;

  const bool use_ws = (d_ws != nullptr) && (ws_size >= WS_BYTES);
  if (use_ws) {
    bilinear_kern<<<512, 512, 0, stream>>>(x, y, w, out, (float*)d_ws, 1);
    reduce_ws<<<128, 256, 0, stream>>>(bias, (const f32x4*)d_ws, out);
  } else {
    init_out<<<512, 256, 0, stream>>>(bias, out);
    bilinear_kern<<<512, 512, 0, stream>>>(x, y, w, out, nullptr, 0);
  }
}